// Round 11
// baseline (173.660 us; speedup 1.0000x reference)
//
#include <hip/hip_runtime.h>

#define NN 100000
#define NE 1000000
#define D  64
#define CAP 32          // per-node bucket capacity; Poisson(10) ⇒ P(deg>32) ≈ 2e-9/node
#define OVF_CAP 16384

#define FILL_EPT 8                                        // edges per thread
#define FILL_CHUNK (256 * FILL_EPT)                       // 2048
#define FILL_NCHUNK ((NE + FILL_CHUNK - 1) / FILL_CHUNK)  // 489
#define PART_SZ 12500                                     // NN/8

// ======================= bf16 helpers (RNE pack, shift unpack) =======================
__device__ __forceinline__ unsigned bf16rne(float f) {
    unsigned h = __float_as_uint(f);
    return (h + 0x7fffu + ((h >> 16) & 1u)) >> 16;
}
__device__ __forceinline__ uint2 pack4(float4 v) {
    uint2 o;
    o.x = bf16rne(v.x) | (bf16rne(v.y) << 16);
    o.y = bf16rne(v.z) | (bf16rne(v.w) << 16);
    return o;
}
__device__ __forceinline__ float4 unpack4(uint2 u) {
    float4 f;
    f.x = __uint_as_float(u.x << 16);
    f.y = __uint_as_float(u.x & 0xffff0000u);
    f.z = __uint_as_float(u.y << 16);
    f.w = __uint_as_float(u.y & 0xffff0000u);
    return f;
}

// ======================= bucket build: XCD-partitioned writes =======================
// dst/src are streamed NONTEMPORAL so they don't evict partially-filled bucket
// lines from the XCD's L2 (round-10 counters: 46 MB writes for 4 MB payload =
// mid-fill eviction). Partition region/XCD = 1.6 MB -> stays L2-resident.
__global__ __launch_bounds__(256) void k_fill_bucket(const int* __restrict__ src,
                                                     const int* __restrict__ dst,
                                                     int* __restrict__ cnt,
                                                     int* __restrict__ bucket,
                                                     int* __restrict__ ovf_n,
                                                     int2* __restrict__ ovf) {
    const int part = blockIdx.x & 7;
    const int lo = part * PART_SZ, hi = lo + PART_SZ;
    const int base = (blockIdx.x >> 3) * FILL_CHUNK + threadIdx.x;
    #pragma unroll
    for (int it = 0; it < FILL_EPT; ++it) {
        int e = base + it * 256;
        if (e < NE) {
            int d = __builtin_nontemporal_load(&dst[e]);
            if (d >= lo && d < hi) {
                int s = __builtin_nontemporal_load(&src[e]);
                int c = atomicAdd(&cnt[d], 1);
                if (c < CAP) {
                    bucket[(size_t)d * CAP + c] = s;
                } else {                                 // ~never
                    int i = atomicAdd(ovf_n, 1);
                    if (i < OVF_CAP) ovf[i] = make_int2(s, d);
                }
            }
        }
    }
}

// ======================= fp32 -> bf16 convert (x -> P) + dinv =======================
// grid 12500*256 == NN*32 exactly; first NN threads also compute dinv.
__global__ void k_cvt(const float2* __restrict__ x2, unsigned* __restrict__ xb,
                      const int* __restrict__ cnt, float* __restrict__ dinv) {
    int i = blockIdx.x * blockDim.x + threadIdx.x;
    unsigned long long v = __builtin_nontemporal_load((const unsigned long long*)&x2[i]);
    float vx = __uint_as_float((unsigned)(v & 0xffffffffu));
    float vy = __uint_as_float((unsigned)(v >> 32));
    xb[i] = bf16rne(vx) | (bf16rne(vy) << 16);
    if (i < NN) dinv[i] = rsqrtf((float)(cnt[i] + 1));   // +1 self loop
}

// ======================= propagation (pull, bf16 rows, fp32 accum) =======================
// out[n] = dinv[n] * ( dinv[n]*in[n] + sum_{s in N(n)} dinv[s]*in[s] )

__global__ __launch_bounds__(256) void k_gather_bf16(const uint2* __restrict__ in2,
                                                     const int* __restrict__ cnt,
                                                     const int* __restrict__ bucket,
                                                     const float* __restrict__ dinv,
                                                     const int* __restrict__ ovf_n,
                                                     const int2* __restrict__ ovf,
                                                     uint2* __restrict__ out2) {
    const int tid = threadIdx.x;
    const int l = tid & 15;
    const int n = blockIdx.x * 16 + (tid >> 4);   // 6250*16 == NN exactly

    const int deg = min(cnt[n], CAP);
    const float dn = dinv[n];

    float4 a0 = unpack4(in2[(size_t)n * 16 + l]);
    a0.x *= dn; a0.y *= dn; a0.z *= dn; a0.w *= dn;
    float4 a1 = make_float4(0.f, 0.f, 0.f, 0.f);
    float4 a2 = make_float4(0.f, 0.f, 0.f, 0.f);
    float4 a3 = make_float4(0.f, 0.f, 0.f, 0.f);

    if (deg > 0) {
        int   iA = (l < deg) ? l : 0;
        int   sA = bucket[(size_t)n * CAP + iA];
        float wA = dinv[sA];
        const int kmax = deg < 16 ? deg : 16;
        int k = 0;
        for (; k + 3 < kmax; k += 4) {
            int   s0 = __shfl(sA, k + 0, 16);
            int   s1 = __shfl(sA, k + 1, 16);
            int   s2 = __shfl(sA, k + 2, 16);
            int   s3 = __shfl(sA, k + 3, 16);
            float w0 = __shfl(wA, k + 0, 16);
            float w1 = __shfl(wA, k + 1, 16);
            float w2 = __shfl(wA, k + 2, 16);
            float w3 = __shfl(wA, k + 3, 16);
            float4 r0 = unpack4(in2[(size_t)s0 * 16 + l]);
            float4 r1 = unpack4(in2[(size_t)s1 * 16 + l]);
            float4 r2 = unpack4(in2[(size_t)s2 * 16 + l]);
            float4 r3 = unpack4(in2[(size_t)s3 * 16 + l]);
            a0.x = fmaf(w0, r0.x, a0.x); a0.y = fmaf(w0, r0.y, a0.y);
            a0.z = fmaf(w0, r0.z, a0.z); a0.w = fmaf(w0, r0.w, a0.w);
            a1.x = fmaf(w1, r1.x, a1.x); a1.y = fmaf(w1, r1.y, a1.y);
            a1.z = fmaf(w1, r1.z, a1.z); a1.w = fmaf(w1, r1.w, a1.w);
            a2.x = fmaf(w2, r2.x, a2.x); a2.y = fmaf(w2, r2.y, a2.y);
            a2.z = fmaf(w2, r2.z, a2.z); a2.w = fmaf(w2, r2.w, a2.w);
            a3.x = fmaf(w3, r3.x, a3.x); a3.y = fmaf(w3, r3.y, a3.y);
            a3.z = fmaf(w3, r3.z, a3.z); a3.w = fmaf(w3, r3.w, a3.w);
        }
        for (; k < kmax; ++k) {
            int   s0 = __shfl(sA, k, 16);
            float w0 = __shfl(wA, k, 16);
            float4 r0 = unpack4(in2[(size_t)s0 * 16 + l]);
            a0.x = fmaf(w0, r0.x, a0.x); a0.y = fmaf(w0, r0.y, a0.y);
            a0.z = fmaf(w0, r0.z, a0.z); a0.w = fmaf(w0, r0.w, a0.w);
        }
        if (deg > 16) {   // ~3% of nodes
            int   iB = (16 + l < deg) ? (16 + l) : 0;
            int   sB = bucket[(size_t)n * CAP + iB];
            float wB = dinv[sB];
            const int k2max = deg - 16;
            int k2 = 0;
            for (; k2 + 1 < k2max; k2 += 2) {
                int   s0 = __shfl(sB, k2 + 0, 16);
                int   s1 = __shfl(sB, k2 + 1, 16);
                float w0 = __shfl(wB, k2 + 0, 16);
                float w1 = __shfl(wB, k2 + 1, 16);
                float4 r0 = unpack4(in2[(size_t)s0 * 16 + l]);
                float4 r1 = unpack4(in2[(size_t)s1 * 16 + l]);
                a1.x = fmaf(w0, r0.x, a1.x); a1.y = fmaf(w0, r0.y, a1.y);
                a1.z = fmaf(w0, r0.z, a1.z); a1.w = fmaf(w0, r0.w, a1.w);
                a2.x = fmaf(w1, r1.x, a2.x); a2.y = fmaf(w1, r1.y, a2.y);
                a2.z = fmaf(w1, r1.z, a2.z); a2.w = fmaf(w1, r1.w, a2.w);
            }
            if (k2 < k2max) {
                int   s0 = __shfl(sB, k2, 16);
                float w0 = __shfl(wB, k2, 16);
                float4 r0 = unpack4(in2[(size_t)s0 * 16 + l]);
                a3.x = fmaf(w0, r0.x, a3.x); a3.y = fmaf(w0, r0.y, a3.y);
                a3.z = fmaf(w0, r0.z, a3.z); a3.w = fmaf(w0, r0.w, a3.w);
            }
        }
    }

    // inline overflow fixup (ovf_n is ~always 0; one hot scalar load)
    int m = *ovf_n;
    if (m > 0) {
        if (m > OVF_CAP) m = OVF_CAP;
        for (int i = 0; i < m; ++i) {
            int2 p = ovf[i];
            if (p.y == n) {
                float w = dinv[p.x];
                float4 r = unpack4(in2[(size_t)p.x * 16 + l]);
                a0.x = fmaf(w, r.x, a0.x); a0.y = fmaf(w, r.y, a0.y);
                a0.z = fmaf(w, r.z, a0.z); a0.w = fmaf(w, r.w, a0.w);
            }
        }
    }

    float4 r;
    r.x = dn * ((a0.x + a1.x) + (a2.x + a3.x));
    r.y = dn * ((a0.y + a1.y) + (a2.y + a3.y));
    r.z = dn * ((a0.z + a1.z) + (a2.z + a3.z));
    r.w = dn * ((a0.w + a1.w) + (a2.w + a3.w));
    out2[(size_t)n * 16 + l] = pack4(r);
}

// ======================= linear: W in registers, readlane row broadcast =======================
__global__ __launch_bounds__(256) void k_linear_reg(const unsigned short* __restrict__ inb,
                                                    const float* __restrict__ W,
                                                    const float* __restrict__ bias,
                                                    float* __restrict__ out) {
    const int lane = threadIdx.x & 63;
    const int wid  = (blockIdx.x * blockDim.x + threadIdx.x) >> 6;
    const int nw   = (gridDim.x * blockDim.x) >> 6;

    float w[64];
    const float4* W4 = (const float4*)W;
    #pragma unroll
    for (int i = 0; i < 16; ++i) {
        float4 q = W4[lane * 16 + i];
        w[4 * i + 0] = q.x; w[4 * i + 1] = q.y;
        w[4 * i + 2] = q.z; w[4 * i + 3] = q.w;
    }
    const float bo = bias[lane];

    for (int n = wid; n < NN; n += nw) {
        unsigned short rh = __builtin_nontemporal_load(&inb[(size_t)n * 64 + lane]);
        int rli = (int)((unsigned)rh << 16);
        float y0 = bo, y1 = 0.f;
        #pragma unroll
        for (int i = 0; i < 64; i += 2) {
            y0 = fmaf(__int_as_float(__builtin_amdgcn_readlane(rli, i)),     w[i],     y0);
            y1 = fmaf(__int_as_float(__builtin_amdgcn_readlane(rli, i + 1)), w[i + 1], y1);
        }
        __builtin_nontemporal_store(y0 + y1, &out[(size_t)n * 64 + lane]);
    }
}

// ======================= fallback path (atomic scatter, fp32) =======================

__global__ void k_init_deg(float* __restrict__ deg) {
    int n = blockIdx.x * blockDim.x + threadIdx.x;
    if (n < NN) deg[n] = 1.0f;
}
__global__ void k_count_deg(const int* __restrict__ dst, float* __restrict__ deg) {
    int e = blockIdx.x * blockDim.x + threadIdx.x;
    if (e < NE) atomicAdd(&deg[dst[e]], 1.0f);
}
__global__ void k_dinv_f(float* __restrict__ deg) {
    int n = blockIdx.x * blockDim.x + threadIdx.x;
    if (n < NN) deg[n] = rsqrtf(deg[n]);
}
__global__ void k_prop_init(const float* __restrict__ in, const float* __restrict__ dinv,
                            float* __restrict__ out) {
    int i = blockIdx.x * blockDim.x + threadIdx.x;
    if (i < NN * D) {
        int n = i >> 6;
        float di = dinv[n];
        out[i] = di * di * in[i];
    }
}
__global__ __launch_bounds__(256) void k_prop_edges(const float* __restrict__ in,
                                                    const int* __restrict__ src,
                                                    const int* __restrict__ dst,
                                                    const float* __restrict__ dinv,
                                                    float* __restrict__ out) {
    int t = blockIdx.x * blockDim.x + threadIdx.x;
    int e = t >> 6, f = t & 63;
    if (e < NE) {
        int s = src[e], d = dst[e];
        float w = dinv[s] * dinv[d];
        atomicAdd(&out[d * D + f], w * in[s * D + f]);
    }
}
__global__ __launch_bounds__(256) void k_linear(const float* __restrict__ in,
                                                const float* __restrict__ W,
                                                const float* __restrict__ bias,
                                                float* __restrict__ out) {
    __shared__ float Wt[64 * 65];
    __shared__ float rows[4][64];
    const int tid = threadIdx.x;
    for (int m = tid; m < 64 * 64; m += 256) {
        int o = m >> 6, i = m & 63;
        Wt[i * 65 + o] = W[m];
    }
    __syncthreads();
    const int wave = tid >> 6, lane = tid & 63;
    const float bo = bias[lane];
    for (int base = blockIdx.x * 4; base < NN; base += gridDim.x * 4) {
        int n = base + wave;
        if (n < NN) {
            rows[wave][lane] = in[n * D + lane];
            float acc = bo;
            #pragma unroll
            for (int i = 0; i < 64; ++i)
                acc = fmaf(rows[wave][i], Wt[i * 65 + lane], acc);
            out[n * D + lane] = acc;
        }
    }
}

// ======================= launch =======================

extern "C" void kernel_launch(void* const* d_in, const int* in_sizes, int n_in,
                              void* d_out, int out_size, void* d_ws, size_t ws_size,
                              hipStream_t stream) {
    const float* x   = (const float*)d_in[0];
    const int*   ei  = (const int*)d_in[1];
    const float* W   = (const float*)d_in[2];
    const float* b   = (const float*)d_in[3];
    float* out = (float*)d_out;

    const int* src = ei;        // edge_index[0]
    const int* dst = ei + NE;   // edge_index[1]

    char* ws = (char*)d_ws;
    size_t off = 0;
    auto take = [&](size_t bytes) -> char* {
        char* p = ws + off;
        off = (off + bytes + 255) & ~(size_t)255;
        return p;
    };

    int*      cnt    = (int*)take((size_t)NN * 4);
    float*    dinv   = (float*)take((size_t)NN * 4);
    int*      ovf_n  = (int*)take(256);
    int2*     ovf    = (int2*)take((size_t)OVF_CAP * 8);
    unsigned* P      = (unsigned*)take((size_t)NN * 32 * 4);   // bf16 buffer (12.8 MB)
    unsigned* Q      = (unsigned*)take((size_t)NN * 32 * 4);   // bf16 buffer (12.8 MB)
    int*      bucket = (int*)take((size_t)NN * CAP * 4);
    float*    buf    = (float*)P;   // fallback fp32 buffer: spans P+Q (25.6 MB, contiguous)
    const bool use_bucket = (off <= ws_size);

    const int B = 256;
    const int gridE1 = (NE + B - 1) / B;   // 3907
    const int gridN1 = (NN + B - 1) / B;   // 391
    const int gridNW = NN / 16;            // 6250

    if (use_bucket) {
        hipMemsetAsync(cnt, 0, (size_t)NN * 4, stream);
        hipMemsetAsync(ovf_n, 0, 4, stream);
        k_fill_bucket<<<FILL_NCHUNK * 8, B, 0, stream>>>(src, dst, cnt, bucket, ovf_n, ovf);
        k_cvt<<<12500, B, 0, stream>>>((const float2*)x, P, cnt, dinv);   // x->P + dinv

        // hop1: P -> Q
        k_gather_bf16<<<gridNW, B, 0, stream>>>((const uint2*)P, cnt, bucket, dinv, ovf_n, ovf, (uint2*)Q);
        // hop2: Q -> P
        k_gather_bf16<<<gridNW, B, 0, stream>>>((const uint2*)Q, cnt, bucket, dinv, ovf_n, ovf, (uint2*)P);
        // hop3: P -> Q
        k_gather_bf16<<<gridNW, B, 0, stream>>>((const uint2*)P, cnt, bucket, dinv, ovf_n, ovf, (uint2*)Q);
        // linear: Q -> out (fp32 W, fp32 accum)
        k_linear_reg<<<1024, B, 0, stream>>>((const unsigned short*)Q, W, b, out);
    } else {
        const int gridF = (NN * D + B - 1) / B;
        const int gridEW = (NE * 64) / B;
        k_init_deg <<<gridN1, B, 0, stream>>>(dinv);
        k_count_deg<<<gridE1, B, 0, stream>>>(dst, dinv);
        k_dinv_f   <<<gridN1, B, 0, stream>>>(dinv);
        k_prop_init <<<gridF, B, 0, stream>>>(x, dinv, buf);
        k_prop_edges<<<gridEW, B, 0, stream>>>(x, src, dst, dinv, buf);
        k_prop_init <<<gridF, B, 0, stream>>>(buf, dinv, out);
        k_prop_edges<<<gridEW, B, 0, stream>>>(buf, src, dst, dinv, out);
        k_prop_init <<<gridF, B, 0, stream>>>(out, dinv, buf);
        k_prop_edges<<<gridEW, B, 0, stream>>>(out, src, dst, dinv, buf);
        k_linear<<<NN / 4, B, 0, stream>>>(buf, W, b, out);
    }
}